// Round 2
// 817.535 us; speedup vs baseline: 1.1803x; 1.1803x over previous
//
#include <hip/hip_runtime.h>

// ---------------------------------------------------------------------------
// TransformerBlock: B=2 T=2048 C=2048 H=16 HD=128 MLP=8192, causal, relu^2 MLP
// Round 6: same footprint as the proven 184.5MB layout (R0's 252MB layout is
// the suspected page-fault cause). Weights pre-converted to bf16 into DEAD
// aliased regions; all GEMMs use the BK=64 m97-class core with
// global_load_lds(16B) for BOTH operands + both-sides XOR slot swizzle.
// Split-K + reduce replaced by fused-residual GEMM epilogues (no partials).
//
// mfma_f32_16x16x32_bf16 layouts (learn_hip m89/m91):
//   A[m=lane&15][k=(lane>>4)*8+j], B[n=lane&15][k=(lane>>4)*8+j]
//   D[row=(lane>>4)*4+reg][col=lane&15]
//
// Workspace (184.5 MB, identical to prior working kernel):
//   flag(256B) | h | qb | kb | vt | ao | x1(f32) | mm(2*FCE bf16)
// Aliases (lifetime-checked):
//   wqkvo_b = mm      (live: start .. wo GEMM;  mm written by fc1 GEMM later)
//   fc1b    = qb..kb  (converted after attn;    live .. fc1 GEMM)
//   fc2b    = vt..ao  (converted after wo GEMM; live .. fc2 GEMM)
// ---------------------------------------------------------------------------

typedef __bf16 bf16x8 __attribute__((ext_vector_type(8)));
typedef __bf16 bf16x4 __attribute__((ext_vector_type(4)));
typedef float  f32x4  __attribute__((ext_vector_type(4)));

static __device__ __forceinline__ __bf16 tobf(float f) { return (__bf16)f; }

// async 16B global->LDS; lptr wave-uniform, HW writes lane l at lptr + l*16.
static __device__ __forceinline__ void async_copy16(const void* g, void* l) {
    __builtin_amdgcn_global_load_lds(
        (const __attribute__((address_space(1))) void*)g,
        (__attribute__((address_space(3))) void*)l, 16, 0, 0);
}

// ---------------------------------------------------------------------------
__global__ void detect_dtype_kernel(const unsigned short* __restrict__ xh,
                                    int* __restrict__ flag) {
    int t = threadIdx.x;                       // one wave of 64
    unsigned short u = xh[2 * t];              // even ushort slots
    int e = (u >> 7) & 0xFF;                   // bf16 exponent field
    bool outlier = (e < 100) || (e > 131);     // implausible for N(0,1)
    unsigned long long m = __ballot(outlier);
    if (t == 0) *flag = (__popcll(m) >= 16) ? 1 : 0;   // 1 => fp32 buffers
}

// ---------------------------------------------------------------------------
// Weight conversion, 8 elems/thread.
// convert_w4: y=0..3 -> wq/wk/wv/wo into dqkvo + y*CC (grid 2048 x 4)
__global__ __launch_bounds__(256) void convert_w4(
    const void* __restrict__ w0, const void* __restrict__ w1,
    const void* __restrict__ w2, const void* __restrict__ w3,
    __bf16* __restrict__ dqkvo, const int* __restrict__ flagp) {
    constexpr size_t CC = (size_t)2048 * 2048;
    const int y = blockIdx.y;
    size_t i = ((size_t)blockIdx.x * 256 + threadIdx.x) * 8;
    const void* s = (y == 0) ? w0 : (y == 1) ? w1 : (y == 2) ? w2 : w3;
    __bf16* d = dqkvo + (size_t)y * CC;
    if (*flagp != 0) {
        const float4* sp = (const float4*)((const float*)s + i);
        float4 a = sp[0], b = sp[1];
        bf16x8 o = {tobf(a.x), tobf(a.y), tobf(a.z), tobf(a.w),
                    tobf(b.x), tobf(b.y), tobf(b.z), tobf(b.w)};
        *(bf16x8*)(d + i) = o;
    } else {
        *(bf16x8*)(d + i) = *(const bf16x8*)((const __bf16*)s + i);
    }
}

// single matrix of FCE = 16,777,216 elems (grid 8192)
__global__ __launch_bounds__(256) void convert_w1(
    const void* __restrict__ src, __bf16* __restrict__ dst,
    const int* __restrict__ flagp) {
    size_t i = ((size_t)blockIdx.x * 256 + threadIdx.x) * 8;
    if (*flagp != 0) {
        const float4* sp = (const float4*)((const float*)src + i);
        float4 a = sp[0], b = sp[1];
        bf16x8 o = {tobf(a.x), tobf(a.y), tobf(a.z), tobf(a.w),
                    tobf(b.x), tobf(b.y), tobf(b.z), tobf(b.w)};
        *(bf16x8*)(dst + i) = o;
    } else {
        *(bf16x8*)(dst + i) = *(const bf16x8*)((const __bf16*)src + i);
    }
}

// ---------------------------------------------------------------------------
// rmsnorm: row of C=2048, one block per row, 256 threads x 8 elements.
template <int SRC>
__global__ __launch_bounds__(256) void rmsnorm_kernel(
    const void* __restrict__ xp, __bf16* __restrict__ h,
    const int* __restrict__ flagp) {
    constexpr int C = 2048;
    const int row = blockIdx.x, t = threadIdx.x;
    float vals[8];
    bool f32in = (SRC == 1) || (*flagp != 0);
    if (f32in) {
        const float4* xr = (const float4*)((const float*)xp + (size_t)row * C);
        float4 a = xr[2 * t], b = xr[2 * t + 1];
        vals[0] = a.x; vals[1] = a.y; vals[2] = a.z; vals[3] = a.w;
        vals[4] = b.x; vals[5] = b.y; vals[6] = b.z; vals[7] = b.w;
    } else {
        bf16x8 a = *((const bf16x8*)((const __bf16*)xp + (size_t)row * C) + t);
#pragma unroll
        for (int j = 0; j < 8; ++j) vals[j] = (float)a[j];
    }
    float ss = 0.f;
#pragma unroll
    for (int j = 0; j < 8; ++j) ss += vals[j] * vals[j];
#pragma unroll
    for (int off = 32; off > 0; off >>= 1) ss += __shfl_down(ss, off);
    __shared__ float red[4];
    if ((t & 63) == 0) red[t >> 6] = ss;
    __syncthreads();
    float mean = (red[0] + red[1] + red[2] + red[3]) * (1.0f / C);
    float sc = rsqrtf(mean + 1e-5f);
    bf16x8 o;
#pragma unroll
    for (int j = 0; j < 8; ++j) o[j] = tobf(vals[j] * sc);
    *((bf16x8*)(h + (size_t)row * C) + t) = o;
}

// ---------------------------------------------------------------------------
// Shared 128x128 tile core, BK=64, 4 waves, bf16 A and W (both [rows][K]).
// LDS tiles use a 16B-slot XOR swizzle: data of logical slot l in row r sits
// at physical slot l ^ (r&7).  global_load_lds writes LDS linearly
// (base + lane*16), so the *global source* slot is pre-swizzled per lane and
// the ds_read applies the same XOR -> 2-way bank aliasing only (free, m136).
static __device__ __forceinline__ void gemm_core_128(
    const __bf16* __restrict__ A, const __bf16* __restrict__ W,
    int m0, int n0, int K,
    __bf16 (*As)[64], __bf16 (*Bs)[64], f32x4 (&acc)[4][4]) {
    const int t = threadIdx.x;
    const int wave = t >> 6, lane = t & 63;
    const int lr = lane & 15, lq = lane >> 4;
    const int wm = wave & 1, wn = wave >> 1;

    // staging: 1024 16B chunks per tile; 4 per thread per operand.
    const __bf16* gA[4];
    const __bf16* gB[4];
    int lo[4];
#pragma unroll
    for (int i = 0; i < 4; ++i) {
        int c = i * 256 + t;                  // chunk index
        int row = c >> 3;                     // LDS row (128B rows)
        int sl = (c & 7) ^ (row & 7);         // logical slot feeding this phys slot
        gA[i] = A + (size_t)(m0 + row) * K + sl * 8;
        gB[i] = W + (size_t)(n0 + row) * K + sl * 8;
        lo[i] = (c & ~63) * 8;                // wave-uniform LDS elem offset
    }
    const int sx = lr & 7;                    // read-side XOR (row&7 == lr&7)

    const f32x4 zero = {0.f, 0.f, 0.f, 0.f};
#pragma unroll
    for (int i = 0; i < 4; ++i)
#pragma unroll
        for (int j = 0; j < 4; ++j) acc[i][j] = zero;

    for (int k0 = 0; k0 < K; k0 += 64) {
#pragma unroll
        for (int i = 0; i < 4; ++i) {
            async_copy16(gA[i] + k0, &As[0][0] + lo[i]);
            async_copy16(gB[i] + k0, &Bs[0][0] + lo[i]);
        }
        __syncthreads();
#pragma unroll
        for (int kk = 0; kk < 2; ++kk) {
            const int sp = ((kk * 4 + lq) ^ sx) * 8;  // swizzled 16B slot
            bf16x8 a[4], b[4];
#pragma unroll
            for (int ii = 0; ii < 4; ++ii) {
                a[ii] = *(const bf16x8*)&As[wm * 64 + ii * 16 + lr][sp];
                b[ii] = *(const bf16x8*)&Bs[wn * 64 + ii * 16 + lr][sp];
            }
#pragma unroll
            for (int ii = 0; ii < 4; ++ii)
#pragma unroll
                for (int jj = 0; jj < 4; ++jj)
                    acc[ii][jj] = __builtin_amdgcn_mfma_f32_16x16x32_bf16(
                        a[ii], b[jj], acc[ii][jj], 0, 0, 0);
        }
        __syncthreads();
    }
}

// ---------------------------------------------------------------------------
// NT GEMM: out = A[M,K](bf16) @ W[N,K]^T (bf16). No split-K.
// EPI 2: bf16 relu(acc)^2                         (fc1 -> mm)
// EPI 5: fp32 out = acc + res (res dtype per flag) (wo  -> x1, res = x)
// EPI 6: out = acc + res_f32; out dtype per flag   (fc2 -> d_out, res = x1)
template <int EPI>
__global__ __launch_bounds__(256) void gemm_nt(
    const __bf16* __restrict__ A, const __bf16* __restrict__ W,
    void* __restrict__ outp, const void* __restrict__ resp,
    int M, int N, int K, const int* __restrict__ flagp) {
    __shared__ __align__(16) __bf16 As[128][64];
    __shared__ __align__(16) __bf16 Bs[128][64];
    const int t = threadIdx.x;
    const int wave = t >> 6, lane = t & 63;
    const int lr = lane & 15, lq = lane >> 4;
    const int wm = wave & 1, wn = wave >> 1;
    const int m0 = blockIdx.y * 128, n0 = blockIdx.x * 128;

    f32x4 acc[4][4];
    gemm_core_128(A, W, m0, n0, K, As, Bs, acc);

    const bool f32 = (EPI == 2) ? false : (*flagp != 0);
#pragma unroll
    for (int i = 0; i < 4; ++i)
#pragma unroll
        for (int j = 0; j < 4; ++j)
#pragma unroll
            for (int r = 0; r < 4; ++r) {
                int row = m0 + wm * 64 + i * 16 + lq * 4 + r;
                int col = n0 + wn * 64 + j * 16 + lr;
                size_t off = (size_t)row * N + col;
                float v = acc[i][j][r];
                if (EPI == 2) {
                    float rv = v > 0.f ? v : 0.f;
                    ((__bf16*)outp)[off] = tobf(rv * rv);
                } else if (EPI == 5) {
                    float res = f32 ? ((const float*)resp)[off]
                                    : (float)((const __bf16*)resp)[off];
                    ((float*)outp)[off] = v + res;
                } else {  // EPI == 6
                    float o = v + ((const float*)resp)[off];
                    if (f32) ((float*)outp)[off] = o;
                    else     ((__bf16*)outp)[off] = tobf(o);
                }
            }
}

// ---------------------------------------------------------------------------
// Fused QKV GEMM: grid (48, 32). which = bx>>4 selects weight/output.
// Weights pre-converted bf16, packed at Wall + which*C*C.
// Q output is PRE-SCALED by log2(e)/sqrt(HD) so attention softmax is exp2.
// V output is stored TRANSPOSED: Vt[(b*2048 + h*128+d)*2048 + t].
__global__ __launch_bounds__(256) void gemm_qkv(
    const __bf16* __restrict__ A, const __bf16* __restrict__ Wall,
    __bf16* __restrict__ qout, __bf16* __restrict__ kout,
    __bf16* __restrict__ vtout) {
    constexpr int N = 2048, K = 2048;
    constexpr float kQScale = 1.4426950408889634f * 0.08838834764831845f;
    __shared__ __align__(16) __bf16 As[128][64];
    __shared__ __align__(16) __bf16 Bs[128][64];
    const int t = threadIdx.x;
    const int wave = t >> 6, lane = t & 63;
    const int lr = lane & 15, lq = lane >> 4;
    const int wm = wave & 1, wn = wave >> 1;
    const int which = blockIdx.x >> 4;
    const int m0 = blockIdx.y * 128, n0 = (blockIdx.x & 15) * 128;
    const __bf16* W = Wall + (size_t)which * N * K;

    f32x4 acc[4][4];
    gemm_core_128(A, W, m0, n0, K, As, Bs, acc);

    if (which < 2) {
        __bf16* outp = (which == 0) ? qout : kout;
        const float sc = (which == 0) ? kQScale : 1.0f;
#pragma unroll
        for (int i = 0; i < 4; ++i)
#pragma unroll
            for (int j = 0; j < 4; ++j)
#pragma unroll
                for (int r = 0; r < 4; ++r) {
                    int row = m0 + wm * 64 + i * 16 + lq * 4 + r;
                    int col = n0 + wn * 64 + j * 16 + lr;
                    outp[(size_t)row * N + col] = tobf(acc[i][j][r] * sc);
                }
    } else {
#pragma unroll
        for (int i = 0; i < 4; ++i)
#pragma unroll
            for (int j = 0; j < 4; ++j) {
                int t0 = m0 + wm * 64 + i * 16 + lq * 4;   // token index (4 consec)
                int b  = t0 >> 11, tt = t0 & 2047;
                int col = n0 + wn * 64 + j * 16 + lr;      // h*128 + d
                bf16x4 p = {tobf(acc[i][j][0]), tobf(acc[i][j][1]),
                            tobf(acc[i][j][2]), tobf(acc[i][j][3])};
                *(bf16x4*)(vtout + (((size_t)(b * 2048 + col)) << 11) + tt) = p;
            }
    }
}

// ---------------------------------------------------------------------------
// Causal flash attention, load-balanced. Grid (16, H, B), block 256 (4 waves).
// Each block runs TWO q-tiles: blockIdx.x and 31-blockIdx.x -> uniform 33
// k-iterations per block. Q is pre-scaled (log2 domain, exp2 softmax).
// V pre-transposed: Vt[(b*2048 + h*128 + d)*2048 + t].
// Row-sums l accumulate via a ones-column MFMA alongside O (same rescaling).
__global__ __launch_bounds__(256) void attn_kernel(
    const __bf16* __restrict__ Q, const __bf16* __restrict__ K,
    const __bf16* __restrict__ Vt, __bf16* __restrict__ O) {
    constexpr int T = 2048, C = 2048, HD = 128;
    __shared__ __align__(16) __bf16 Ks[64][136];
    __shared__ __align__(16) __bf16 Vts[128][72];
    __shared__ __align__(16) __bf16 Ps[4][16][72];
    const int t = threadIdx.x, w = t >> 6, lane = t & 63;
    const int lr = lane & 15, lq = lane >> 4;
    const int b = blockIdx.z, h = blockIdx.y;
    const __bf16* vtb = Vt + ((size_t)(b * 2048 + h * 128) << 11);
    const f32x4 zero = {0.f, 0.f, 0.f, 0.f};

    // ones B-fragment: B[n][k] = (n==0), for the l-accumulator column
    bf16x8 ones;
#pragma unroll
    for (int j = 0; j < 8; ++j) ones[j] = (lr == 0) ? (__bf16)1.0f : (__bf16)0.0f;

    for (int pass = 0; pass < 2; ++pass) {
        const int qblk = (pass == 0) ? blockIdx.x : 31 - blockIdx.x;
        const int q0 = qblk * 64;

        const int qrow = q0 + w * 16 + lr;
        const __bf16* qb = Q + (size_t)(b * T + qrow) * C + h * HD;
        bf16x8 qf[4];
#pragma unroll
        for (int s = 0; s < 4; ++s)
            qf[s] = *(const bf16x8*)(qb + s * 32 + lq * 8);

        f32x4 oacc[8], lacc = zero;
#pragma unroll
        for (int nc = 0; nc < 8; ++nc) oacc[nc] = zero;
        float m_i[4] = {-3e38f, -3e38f, -3e38f, -3e38f};

        for (int kb = 0; kb <= qblk; ++kb) {
            const int k00 = kb * 64;
#pragma unroll
            for (int i = 0; i < 4; ++i) {
                int c = t + 256 * i;
                int r = c >> 4, col = (c & 15) * 8;
                *(bf16x8*)&Ks[r][col] =
                    *(const bf16x8*)(K + (size_t)(b * T + k00 + r) * C + h * HD + col);
            }
#pragma unroll
            for (int i = 0; i < 4; ++i) {
                int c = t + 256 * i;
                int r = c >> 3, cg = (c & 7) * 8;
                *(bf16x8*)&Vts[r][cg] =
                    *(const bf16x8*)(vtb + ((size_t)r << 11) + k00 + cg);
            }
            __syncthreads();

            float pv[4][4];
#pragma unroll
            for (int jc = 0; jc < 4; ++jc) {
                f32x4 s = zero;
#pragma unroll
                for (int ks = 0; ks < 4; ++ks) {
                    bf16x8 kf = *(const bf16x8*)&Ks[jc * 16 + lr][ks * 32 + lq * 8];
                    s = __builtin_amdgcn_mfma_f32_16x16x32_bf16(qf[ks], kf, s, 0, 0, 0);
                }
#pragma unroll
                for (int r = 0; r < 4; ++r) pv[jc][r] = s[r];
            }
            if (kb == qblk) {   // diagonal block: causal mask (wave-uniform branch)
#pragma unroll
                for (int jc = 0; jc < 4; ++jc)
#pragma unroll
                    for (int r = 0; r < 4; ++r)
                        if (jc * 16 + lr > w * 16 + lq * 4 + r) pv[jc][r] = -3e38f;
            }
            float rmax[4];
#pragma unroll
            for (int r = 0; r < 4; ++r)
                rmax[r] = fmaxf(fmaxf(pv[0][r], pv[1][r]), fmaxf(pv[2][r], pv[3][r]));
#pragma unroll
            for (int off = 1; off < 16; off <<= 1)
#pragma unroll
                for (int r = 0; r < 4; ++r)
                    rmax[r] = fmaxf(rmax[r], __shfl_xor(rmax[r], off));
            float alpha[4];
#pragma unroll
            for (int r = 0; r < 4; ++r) {
                float mn = fmaxf(m_i[r], rmax[r]);
                alpha[r] = exp2f(m_i[r] - mn);
                m_i[r] = mn;
            }
#pragma unroll
            for (int jc = 0; jc < 4; ++jc)
#pragma unroll
                for (int r = 0; r < 4; ++r)
                    Ps[w][lq * 4 + r][jc * 16 + lr] = tobf(exp2f(pv[jc][r] - m_i[r]));
#pragma unroll
            for (int nc = 0; nc < 8; ++nc)
#pragma unroll
                for (int r = 0; r < 4; ++r) oacc[nc][r] *= alpha[r];
#pragma unroll
            for (int r = 0; r < 4; ++r) lacc[r] *= alpha[r];
            __syncthreads();   // P visible before PV reads

#pragma unroll
            for (int s2 = 0; s2 < 2; ++s2) {
                bf16x8 pa = *(const bf16x8*)&Ps[w][lr][s2 * 32 + lq * 8];
#pragma unroll
                for (int nc = 0; nc < 8; ++nc) {
                    bf16x8 vf = *(const bf16x8*)&Vts[nc * 16 + lr][s2 * 32 + lq * 8];
                    oacc[nc] = __builtin_amdgcn_mfma_f32_16x16x32_bf16(
                        pa, vf, oacc[nc], 0, 0, 0);
                }
                lacc = __builtin_amdgcn_mfma_f32_16x16x32_bf16(pa, ones, lacc, 0, 0, 0);
            }
            __syncthreads();   // PV reads done before next staging overwrite
        }

        // l lives in lanes lr==0 (col 0); broadcast within the 16-lane row group
        float inv[4];
#pragma unroll
        for (int r = 0; r < 4; ++r) inv[r] = 1.0f / __shfl(lacc[r], lane & 48);
#pragma unroll
        for (int nc = 0; nc < 8; ++nc)
#pragma unroll
            for (int r = 0; r < 4; ++r) {
                int row = q0 + w * 16 + lq * 4 + r;
                O[(size_t)(b * T + row) * C + h * HD + nc * 16 + lr] =
                    tobf(oacc[nc][r] * inv[r]);
            }
        __syncthreads();       // pass-1 staging must not race pass-0 epilogue
    }
}

// ---------------------------------------------------------------------------
extern "C" void kernel_launch(void* const* d_in, const int* in_sizes, int n_in,
                              void* d_out, int out_size, void* d_ws, size_t ws_size,
                              hipStream_t stream) {
    const void* x   = d_in[0];
    const void* wq  = d_in[1];
    const void* wk  = d_in[2];
    const void* wv  = d_in[3];
    const void* wo  = d_in[4];
    const void* fc1 = d_in[5];
    const void* fc2 = d_in[6];
    constexpr int Bv = 2, Tv = 2048, Cv = 2048, Hv = 16, MLP = 8192;
    constexpr int M = Bv * Tv;                  // 4096 rows
    constexpr size_t NE = (size_t)M * Cv;       // 8,388,608
    constexpr size_t CC = (size_t)Cv * Cv;      // 4,194,304

    char* ws = (char*)d_ws;
    int*    flag = (int*)ws;                    // 256 B reserved
    __bf16* h    = (__bf16*)(ws + 256);         // NE bf16
    __bf16* qb   = h  + NE;                     // NE bf16
    __bf16* kb   = qb + NE;                     // NE bf16
    __bf16* vt   = kb + NE;                     // NE bf16 (V, pre-transposed)
    __bf16* ao   = vt + NE;                     // NE bf16
    float*  x1   = (float*)(ao + NE);           // NE fp32
    __bf16* mm   = (__bf16*)(x1 + NE);          // M*MLP bf16 (67.1 MB)
    // lifetime aliases (all within the regions above):
    __bf16* wqkvob = mm;   // 4*CC bf16 = 33.55MB, dead before fc1 GEMM writes mm
    __bf16* fc1b   = qb;   // FCE bf16 = qb+kb, converted after attn
    __bf16* fc2b   = vt;   // FCE bf16 = vt+ao, converted after wo GEMM

    detect_dtype_kernel<<<1, 64, 0, stream>>>((const unsigned short*)x, flag);

    // wq/wk/wv/wo -> bf16 packed in mm region (dead until fc1 GEMM)
    convert_w4<<<dim3(2048, 4), 256, 0, stream>>>(wq, wk, wv, wo, wqkvob, flag);

    rmsnorm_kernel<0><<<M, 256, 0, stream>>>(x, h, flag);

    gemm_qkv<<<dim3(48, 32), 256, 0, stream>>>(h, wqkvob, qb, kb, vt);

    attn_kernel<<<dim3(16, Hv, Bv), 256, 0, stream>>>(qb, kb, vt, ao);

    // fc1 -> bf16 into qb+kb (dead after attn)
    convert_w1<<<8192, 256, 0, stream>>>(fc1, fc1b, flag);

    // wo GEMM, fused residual: x1 = ao @ wo^T + x   (fp32 out)
    gemm_nt<5><<<dim3(16, 32), 256, 0, stream>>>(ao, wqkvob + 3 * CC, x1, x,
                                                 M, Cv, Cv, flag);

    // fc2 -> bf16 into vt+ao (dead after wo GEMM)
    convert_w1<<<8192, 256, 0, stream>>>(fc2, fc2b, flag);

    rmsnorm_kernel<1><<<M, 256, 0, stream>>>(x1, h, flag);

    // fc1 GEMM, relu^2 epilogue -> mm (overwrites dead wqkvob)
    gemm_nt<2><<<dim3(64, 32), 256, 0, stream>>>(h, fc1b, mm, nullptr,
                                                 M, MLP, Cv, flag);

    // fc2 GEMM, fused residual: d_out = mm @ fc2^T + x1  (dtype per flag)
    gemm_nt<6><<<dim3(16, 32), 256, 0, stream>>>(mm, fc2b, d_out, x1,
                                                 M, Cv, MLP, flag);
}